// Round 1
// baseline (370.880 us; speedup 1.0000x reference)
//
#include <hip/hip_runtime.h>
#include <math.h>

typedef __attribute__((ext_vector_type(8))) short bf16x8;
typedef __attribute__((ext_vector_type(4))) float f32x4;
typedef __attribute__((ext_vector_type(4))) unsigned short u16x4;

#define MFMA_BF16(a, b, c) __builtin_amdgcn_mfma_f32_16x16x32_bf16((a), (b), (c), 0, 0, 0)

// ---------- helpers ----------
__device__ __forceinline__ unsigned short f2bf_rne(float v) {
    unsigned u = __float_as_uint(v);
    unsigned r = u + 0x7FFFu + ((u >> 16) & 1u);
    return (unsigned short)(r >> 16);
}
__device__ __forceinline__ float bf2f(unsigned short b) {
    return __uint_as_float(((unsigned)b) << 16);
}
// exact for small-integer-valued floats (lower 16 mantissa bits are zero)
__device__ __forceinline__ unsigned short f2bf_exact(float v) {
    return (unsigned short)(__float_as_uint(v) >> 16);
}

// ---------- scale slots ----------
__global__ void init_slots(unsigned* slots) {
    if (threadIdx.x < 2) slots[threadIdx.x] = 0u;
}

__global__ void absmax_kernel(const float* __restrict__ p, int n4, unsigned* __restrict__ slot) {
    float m = 0.f;
    const float4* p4 = (const float4*)p;
    for (int i = blockIdx.x * blockDim.x + threadIdx.x; i < n4; i += gridDim.x * blockDim.x) {
        float4 v = p4[i];
        m = fmaxf(m, fmaxf(fmaxf(fabsf(v.x), fabsf(v.y)), fmaxf(fabsf(v.z), fabsf(v.w))));
    }
#pragma unroll
    for (int off = 32; off > 0; off >>= 1)
        m = fmaxf(m, __shfl_xor(m, off, 64));
    if ((threadIdx.x & 63) == 0) atomicMax(slot, __float_as_uint(m));
}

// W -> clip(round(W/s), -127, 127) stored as bf16 (exact: integer magnitude <= 127)
__global__ void quant_weight_kernel(const float* __restrict__ W, unsigned short* __restrict__ out,
                                    int n4, const unsigned* __restrict__ slot) {
    const float s = __uint_as_float(*slot) / 127.0f;  // match jnp: max|W| / 127.0
    const float4* W4 = (const float4*)W;
    for (int i = blockIdx.x * blockDim.x + threadIdx.x; i < n4; i += gridDim.x * blockDim.x) {
        float4 v = W4[i];
        u16x4 o;
        float q0 = fminf(fmaxf(rintf(v.x / s), -127.f), 127.f);
        float q1 = fminf(fmaxf(rintf(v.y / s), -127.f), 127.f);
        float q2 = fminf(fmaxf(rintf(v.z / s), -127.f), 127.f);
        float q3 = fminf(fmaxf(rintf(v.w / s), -127.f), 127.f);
        o.x = f2bf_exact(q0); o.y = f2bf_exact(q1); o.z = f2bf_exact(q2); o.w = f2bf_exact(q3);
        *(u16x4*)(out + 4 * (size_t)i) = o;
    }
}

// ---------- GEMM: C[m,n] = sum_k A[m,k] * B[n,k]  (NT, K-contiguous both) ----------
// SPLIT_A: A is fp32, decomposed on the fly into bf16 hi+lo (2 MFMAs per frag pair).
// EPI==0: h = acc*s1 + b1[n]; g = gelu(h); q = clip(round(g/sg),-128,127) -> bf16 out.
// EPI==1: y = acc*(sg*s2) + b2[n]; out = clip(round(y/so),-128,127)*so -> fp32 out.
template <bool SPLIT_A, int EPI>
__global__ __launch_bounds__(256, 2) void gemm_nt_kernel(
    const float* __restrict__ Af, const unsigned short* __restrict__ Ab,
    const unsigned short* __restrict__ Bq, const float* __restrict__ bias,
    const unsigned* __restrict__ wmax_slot, const float* __restrict__ sg_ptr,
    const float* __restrict__ so_ptr, unsigned short* __restrict__ out_b,
    float* __restrict__ out_f, int M, int N, int K) {
    __shared__ __align__(16) unsigned short lA[128][40];
    __shared__ __align__(16) unsigned short lAlo[SPLIT_A ? 128 : 1][40];
    __shared__ __align__(16) unsigned short lB[128][40];

    const int tid = threadIdx.x;
    const int lane = tid & 63;
    const int wave = tid >> 6;
    const int wm = (wave >> 1) * 64;   // 2x2 wave grid, 64x64 per wave
    const int wn = (wave & 1) * 64;
    const int lr = lane & 15;
    const int lko = (lane >> 4) * 8;   // k-offset of this lane's 8-elem fragment

    const int m0 = blockIdx.x * 128;
    const int n0 = blockIdx.y * 128;

    f32x4 acc[4][4] = {};

    for (int k0 = 0; k0 < K; k0 += 32) {
        // ---- stage A tile (128 x 32) ----
        if constexpr (SPLIT_A) {
#pragma unroll
            for (int i = 0; i < 4; ++i) {
                int u = tid + i * 256;        // 1024 float4 units
                int r = u >> 3;
                int c = (u & 7) << 2;
                float4 v = *(const float4*)(Af + (size_t)(m0 + r) * K + (k0 + c));
                u16x4 hi, lo;
                {
                    unsigned short h;
                    h = f2bf_rne(v.x); hi.x = h; lo.x = f2bf_rne(v.x - bf2f(h));
                    h = f2bf_rne(v.y); hi.y = h; lo.y = f2bf_rne(v.y - bf2f(h));
                    h = f2bf_rne(v.z); hi.z = h; lo.z = f2bf_rne(v.z - bf2f(h));
                    h = f2bf_rne(v.w); hi.w = h; lo.w = f2bf_rne(v.w - bf2f(h));
                }
                *(u16x4*)&lA[r][c] = hi;
                *(u16x4*)&lAlo[r][c] = lo;
            }
        } else {
#pragma unroll
            for (int i = 0; i < 2; ++i) {
                int u = tid + i * 256;        // 512 bf16x8 units
                int r = u >> 2;
                int c = (u & 3) << 3;
                bf16x8 v = *(const bf16x8*)(Ab + (size_t)(m0 + r) * K + (k0 + c));
                *(bf16x8*)&lA[r][c] = v;
            }
        }
        // ---- stage B tile (128 x 32) ----
#pragma unroll
        for (int i = 0; i < 2; ++i) {
            int u = tid + i * 256;
            int r = u >> 2;
            int c = (u & 3) << 3;
            bf16x8 v = *(const bf16x8*)(Bq + (size_t)(n0 + r) * K + (k0 + c));
            *(bf16x8*)&lB[r][c] = v;
        }
        __syncthreads();

        bf16x8 bfr[4], ah[4], al[4];
#pragma unroll
        for (int i = 0; i < 4; ++i) bfr[i] = *(const bf16x8*)&lB[wn + i * 16 + lr][lko];
#pragma unroll
        for (int i = 0; i < 4; ++i) ah[i] = *(const bf16x8*)&lA[wm + i * 16 + lr][lko];
        if constexpr (SPLIT_A) {
#pragma unroll
            for (int i = 0; i < 4; ++i) al[i] = *(const bf16x8*)&lAlo[wm + i * 16 + lr][lko];
        }
#pragma unroll
        for (int mi = 0; mi < 4; ++mi) {
#pragma unroll
            for (int ni = 0; ni < 4; ++ni) {
                acc[mi][ni] = MFMA_BF16(ah[mi], bfr[ni], acc[mi][ni]);
                if constexpr (SPLIT_A)
                    acc[mi][ni] = MFMA_BF16(al[mi], bfr[ni], acc[mi][ni]);
            }
        }
        __syncthreads();
    }

    // ---- epilogue ----
    const float ws = __uint_as_float(*wmax_slot) / 127.0f;  // weight scale
    if constexpr (EPI == 0) {
        const float sg = *sg_ptr;
#pragma unroll
        for (int mi = 0; mi < 4; ++mi) {
#pragma unroll
            for (int ni = 0; ni < 4; ++ni) {
#pragma unroll
                for (int e = 0; e < 4; ++e) {
                    int m = m0 + wm + mi * 16 + ((lane >> 4) << 2) + e;
                    int n = n0 + wn + ni * 16 + lr;
                    float h = acc[mi][ni][e] * ws + bias[n];
                    float g = 0.5f * h * (1.0f + erff(h / 1.41421356237309515f));
                    float q = rintf(g / sg);
                    q = fminf(fmaxf(q, -128.f), 127.f);
                    out_b[(size_t)m * N + n] = f2bf_exact(q);
                }
            }
        }
    } else {
        const float sg = *sg_ptr;
        const float so = *so_ptr;
        const float sc = sg * ws;
#pragma unroll
        for (int mi = 0; mi < 4; ++mi) {
#pragma unroll
            for (int ni = 0; ni < 4; ++ni) {
#pragma unroll
                for (int e = 0; e < 4; ++e) {
                    int m = m0 + wm + mi * 16 + ((lane >> 4) << 2) + e;
                    int n = n0 + wn + ni * 16 + lr;
                    float y = acc[mi][ni][e] * sc + bias[n];
                    float q = fminf(fmaxf(rintf(y / so), -128.f), 127.f);
                    out_f[(size_t)m * N + n] = q * so;
                }
            }
        }
    }
}

extern "C" void kernel_launch(void* const* d_in, const int* in_sizes, int n_in,
                              void* d_out, int out_size, void* d_ws, size_t ws_size,
                              hipStream_t stream) {
    const float* x  = (const float*)d_in[0];
    const float* W1 = (const float*)d_in[1];
    const float* b1 = (const float*)d_in[2];
    const float* W2 = (const float*)d_in[3];
    const float* b2 = (const float*)d_in[4];
    const float* sg = (const float*)d_in[5];
    const float* so = (const float*)d_in[6];

    const int M = 64 * 196;   // 12544
    const int D = 768;
    const int H = 3072;

    char* ws = (char*)d_ws;
    unsigned* slots = (unsigned*)ws;                                  // [0]=max|W1| [1]=max|W2|
    unsigned short* w1q  = (unsigned short*)(ws + 256);               // H x D bf16 int vals
    unsigned short* w2q  = (unsigned short*)(ws + 256 + (size_t)H * D * 2);  // D x H
    unsigned short* qact = (unsigned short*)(ws + 256 + (size_t)H * D * 4);  // M x H

    init_slots<<<1, 64, 0, stream>>>(slots);
    const int n4w = (H * D) / 4;
    absmax_kernel<<<512, 256, 0, stream>>>(W1, n4w, slots + 0);
    absmax_kernel<<<512, 256, 0, stream>>>(W2, n4w, slots + 1);
    quant_weight_kernel<<<1024, 256, 0, stream>>>(W1, w1q, n4w, slots + 0);
    quant_weight_kernel<<<1024, 256, 0, stream>>>(W2, w2q, n4w, slots + 1);

    dim3 g1(M / 128, H / 128);  // 98 x 24
    gemm_nt_kernel<true, 0><<<g1, 256, 0, stream>>>(
        x, nullptr, w1q, b1, slots + 0, sg, so, qact, nullptr, M, H, D);

    dim3 g2(M / 128, D / 128);  // 98 x 6
    gemm_nt_kernel<false, 1><<<g2, 256, 0, stream>>>(
        nullptr, qact, w2q, b2, slots + 1, sg, so, nullptr, (float*)d_out, M, D, H);
}

// Round 2
// 358.860 us; speedup vs baseline: 1.0335x; 1.0335x over previous
//
#include <hip/hip_runtime.h>
#include <math.h>

typedef __attribute__((ext_vector_type(8))) short bf16x8;
typedef __attribute__((ext_vector_type(4))) float f32x4;
typedef __attribute__((ext_vector_type(4))) unsigned short u16x4;

#define MFMA_BF16(a, b, c) __builtin_amdgcn_mfma_f32_16x16x32_bf16((a), (b), (c), 0, 0, 0)

// ---------- helpers ----------
__device__ __forceinline__ unsigned short f2bf_rne(float v) {
    unsigned u = __float_as_uint(v);
    unsigned r = u + 0x7FFFu + ((u >> 16) & 1u);
    return (unsigned short)(r >> 16);
}
__device__ __forceinline__ float bf2f(unsigned short b) {
    return __uint_as_float(((unsigned)b) << 16);
}
// exact for small-integer-valued floats (lower 16 mantissa bits are zero)
__device__ __forceinline__ unsigned short f2bf_exact(float v) {
    return (unsigned short)(__float_as_uint(v) >> 16);
}

__device__ __forceinline__ void gload16(const void* g, void* l) {
    // direct global->LDS DMA, 16B per lane; LDS dest = wave-uniform base + lane*16
    __builtin_amdgcn_global_load_lds(
        (const __attribute__((address_space(1))) unsigned int*)g,
        (__attribute__((address_space(3))) unsigned int*)l, 16, 0, 0);
}

// ---------- prologue: scales ----------
__global__ void init_slots(unsigned* slots) {
    if (threadIdx.x < 2) slots[threadIdx.x] = 0u;
}

// both weight tensors have the same element count; blockIdx.y selects
__global__ void absmax2_kernel(const float* __restrict__ a, const float* __restrict__ b,
                               int n4, unsigned* __restrict__ slots) {
    const float* p = blockIdx.y ? b : a;
    float m = 0.f;
    const float4* p4 = (const float4*)p;
    for (int i = blockIdx.x * blockDim.x + threadIdx.x; i < n4; i += gridDim.x * blockDim.x) {
        float4 v = p4[i];
        m = fmaxf(m, fmaxf(fmaxf(fabsf(v.x), fabsf(v.y)), fmaxf(fabsf(v.z), fabsf(v.w))));
    }
#pragma unroll
    for (int off = 32; off > 0; off >>= 1)
        m = fmaxf(m, __shfl_xor(m, off, 64));
    if ((threadIdx.x & 63) == 0) atomicMax(slots + blockIdx.y, __float_as_uint(m));
}

// W -> clip(round(W/s), -127, 127) stored as bf16 (exact: integers <= 127)
__global__ void quant2_kernel(const float* __restrict__ Wa, unsigned short* __restrict__ oa,
                              const float* __restrict__ Wb, unsigned short* __restrict__ ob,
                              int n4, const unsigned* __restrict__ slots) {
    const float* W = blockIdx.y ? Wb : Wa;
    unsigned short* out = blockIdx.y ? ob : oa;
    const float s = __uint_as_float(slots[blockIdx.y]) / 127.0f;
    const float4* W4 = (const float4*)W;
    for (int i = blockIdx.x * blockDim.x + threadIdx.x; i < n4; i += gridDim.x * blockDim.x) {
        float4 v = W4[i];
        u16x4 o;
        o.x = f2bf_exact(fminf(fmaxf(rintf(v.x / s), -127.f), 127.f));
        o.y = f2bf_exact(fminf(fmaxf(rintf(v.y / s), -127.f), 127.f));
        o.z = f2bf_exact(fminf(fmaxf(rintf(v.z / s), -127.f), 127.f));
        o.w = f2bf_exact(fminf(fmaxf(rintf(v.w / s), -127.f), 127.f));
        *(u16x4*)(out + 4 * (size_t)i) = o;
    }
}

// x[M][768] fp32 -> xsplit[M][1536] bf16: hi at col k, lo (residual) at col 768+k
__global__ void split_x_kernel(const float* __restrict__ x, unsigned short* __restrict__ out,
                               int n4) {  // n4 = M*768/4
    const float4* x4 = (const float4*)x;
    for (int i = blockIdx.x * blockDim.x + threadIdx.x; i < n4; i += gridDim.x * blockDim.x) {
        int r = i / 192;             // 192 float4 per 768-row
        int c = (i - r * 192) * 4;
        float4 v = x4[i];
        u16x4 hi, lo;
        unsigned short h;
        h = f2bf_rne(v.x); hi.x = h; lo.x = f2bf_rne(v.x - bf2f(h));
        h = f2bf_rne(v.y); hi.y = h; lo.y = f2bf_rne(v.y - bf2f(h));
        h = f2bf_rne(v.z); hi.z = h; lo.z = f2bf_rne(v.z - bf2f(h));
        h = f2bf_rne(v.w); hi.w = h; lo.w = f2bf_rne(v.w - bf2f(h));
        size_t base = (size_t)r * 1536 + c;
        *(u16x4*)(out + base) = hi;
        *(u16x4*)(out + base + 768) = lo;
    }
}

// ---------- GEMM: C[m,n] = sum_k A[m,k] * B[n,(k mod ldb)]  (NT, bf16, m97 structure)
// A is [M][K] bf16; B is [N][ldb] bf16 (ldb<K means A's K concatenates hi|lo halves
// that both multiply the same B, e.g. GEMM1: K=1536, ldb=768).
// EPI==0: h = acc*ws + bias[n]; g = gelu(h); q = clip(round(g/sg),-128,127) -> bf16 out.
// EPI==1: y = acc*(sg*ws) + bias[n]; out = clip(round(y/so),-128,127)*so -> fp32 out.
template <int EPI>
__global__ __launch_bounds__(256, 2) void gemm_nt(
    const unsigned short* __restrict__ A, const unsigned short* __restrict__ B,
    const float* __restrict__ bias, const unsigned* __restrict__ wslot,
    const float* __restrict__ sg_ptr, const float* __restrict__ so_ptr,
    unsigned short* __restrict__ out_b, float* __restrict__ out_f,
    int M, int N, int K, int ldb) {
    __shared__ __align__(16) unsigned short lA[128][32];
    __shared__ __align__(16) unsigned short lB[128][32];

    const int tid = threadIdx.x;
    const int lane = tid & 63;
    const int wave = tid >> 6;
    const int wm = (wave >> 1) * 64;   // 2x2 wave grid, 64x64 per wave
    const int wn = (wave & 1) * 64;
    const int lr = lane & 15;
    const int lko = (lane >> 4) * 8;

    const int m0 = blockIdx.x * 128;
    const int n0 = blockIdx.y * 128;

    // staging coords: 512 x 16B units per tile; unit u -> row u>>2, col (u&3)*8
    const int u0 = tid, u1 = 256 + tid;
    const int r0 = u0 >> 2, c0 = (u0 & 3) << 3;
    const int r1 = u1 >> 2, c1 = (u1 & 3) << 3;
    const size_t aoff0 = (size_t)(m0 + r0) * K + c0;
    const size_t aoff1 = (size_t)(m0 + r1) * K + c1;
    const size_t boff0 = (size_t)(n0 + r0) * ldb + c0;
    const size_t boff1 = (size_t)(n0 + r1) * ldb + c1;
    unsigned short* lA0 = &lA[0][0] + (size_t)(wave * 64) * 8;   // wave-uniform bases
    unsigned short* lA1 = lA0 + 256 * 8;
    unsigned short* lB0 = &lB[0][0] + (size_t)(wave * 64) * 8;
    unsigned short* lB1 = lB0 + 256 * 8;

    f32x4 acc[4][4] = {};

    for (int k0 = 0; k0 < K; k0 += 32) {
        const int bk0 = (k0 >= ldb) ? k0 - ldb : k0;   // uniform scalar
        gload16(A + aoff0 + k0, lA0);
        gload16(A + aoff1 + k0, lA1);
        gload16(B + boff0 + bk0, lB0);
        gload16(B + boff1 + bk0, lB1);
        __syncthreads();   // drains vmcnt(0): LDS tile ready

        bf16x8 af[4], bfr[4];
#pragma unroll
        for (int f = 0; f < 4; ++f) af[f] = *(const bf16x8*)&lA[wm + f * 16 + lr][lko];
#pragma unroll
        for (int f = 0; f < 4; ++f) bfr[f] = *(const bf16x8*)&lB[wn + f * 16 + lr][lko];
#pragma unroll
        for (int mi = 0; mi < 4; ++mi)
#pragma unroll
            for (int ni = 0; ni < 4; ++ni)
                acc[mi][ni] = MFMA_BF16(af[mi], bfr[ni], acc[mi][ni]);
        __syncthreads();   // all reads done before next-tile DMA overwrites
    }

    // ---- epilogue ----
    const float ws = __uint_as_float(*wslot) / 127.0f;
    if constexpr (EPI == 0) {
        const float sg = *sg_ptr;
#pragma unroll
        for (int mi = 0; mi < 4; ++mi)
#pragma unroll
            for (int ni = 0; ni < 4; ++ni)
#pragma unroll
                for (int e = 0; e < 4; ++e) {
                    int m = m0 + wm + mi * 16 + ((lane >> 4) << 2) + e;
                    int n = n0 + wn + ni * 16 + lr;
                    float h = acc[mi][ni][e] * ws + bias[n];
                    float g = 0.5f * h * (1.0f + erff(h / 1.41421356237309515f));
                    float q = fminf(fmaxf(rintf(g / sg), -128.f), 127.f);
                    out_b[(size_t)m * N + n] = f2bf_exact(q);
                }
    } else {
        const float sg = *sg_ptr;
        const float so = *so_ptr;
        const float sc = sg * ws;
#pragma unroll
        for (int mi = 0; mi < 4; ++mi)
#pragma unroll
            for (int ni = 0; ni < 4; ++ni)
#pragma unroll
                for (int e = 0; e < 4; ++e) {
                    int m = m0 + wm + mi * 16 + ((lane >> 4) << 2) + e;
                    int n = n0 + wn + ni * 16 + lr;
                    float y = acc[mi][ni][e] * sc + bias[n];
                    float q = fminf(fmaxf(rintf(y / so), -128.f), 127.f);
                    out_f[(size_t)m * N + n] = q * so;
                }
    }
}

extern "C" void kernel_launch(void* const* d_in, const int* in_sizes, int n_in,
                              void* d_out, int out_size, void* d_ws, size_t ws_size,
                              hipStream_t stream) {
    const float* x  = (const float*)d_in[0];
    const float* W1 = (const float*)d_in[1];
    const float* b1 = (const float*)d_in[2];
    const float* W2 = (const float*)d_in[3];
    const float* b2 = (const float*)d_in[4];
    const float* sg = (const float*)d_in[5];
    const float* so = (const float*)d_in[6];

    const int M = 64 * 196;   // 12544
    const int D = 768;
    const int H = 3072;

    char* ws = (char*)d_ws;
    unsigned* slots = (unsigned*)ws;                              // [0]=max|W1| [1]=max|W2|
    unsigned short* xsplit = (unsigned short*)(ws + 256);         // M x 1536 (hi|lo)
    unsigned short* w1q = xsplit + (size_t)M * 1536;              // H x D
    unsigned short* w2q = w1q + (size_t)H * D;                    // D x H
    unsigned short* qact = w2q + (size_t)D * H;                   // M x H

    init_slots<<<1, 64, 0, stream>>>(slots);
    const int n4w = (H * D) / 4;
    absmax2_kernel<<<dim3(512, 2), 256, 0, stream>>>(W1, W2, n4w, slots);
    quant2_kernel<<<dim3(1024, 2), 256, 0, stream>>>(W1, w1q, W2, w2q, n4w, slots);
    split_x_kernel<<<2048, 256, 0, stream>>>(x, xsplit, (M * D) / 4);

    dim3 g1(M / 128, H / 128);  // 98 x 24
    gemm_nt<0><<<g1, 256, 0, stream>>>(
        xsplit, w1q, b1, slots + 0, sg, so, qact, nullptr, M, H, 2 * D, D);

    dim3 g2(M / 128, D / 128);  // 98 x 6
    gemm_nt<1><<<g2, 256, 0, stream>>>(
        qact, w2q, b2, slots + 1, sg, so, nullptr, (float*)d_out, M, D, H, H);
}

// Round 3
// 357.844 us; speedup vs baseline: 1.0364x; 1.0028x over previous
//
#include <hip/hip_runtime.h>
#include <math.h>

typedef __attribute__((ext_vector_type(8))) short bf16x8;
typedef __attribute__((ext_vector_type(4))) float f32x4;
typedef __attribute__((ext_vector_type(4))) unsigned short u16x4;

#define MFMA_BF16(a, b, c) __builtin_amdgcn_mfma_f32_16x16x32_bf16((a), (b), (c), 0, 0, 0)

// ---------- helpers ----------
__device__ __forceinline__ unsigned short f2bf_rne(float v) {
    unsigned u = __float_as_uint(v);
    unsigned r = u + 0x7FFFu + ((u >> 16) & 1u);
    return (unsigned short)(r >> 16);
}
__device__ __forceinline__ float bf2f(unsigned short b) {
    return __uint_as_float(((unsigned)b) << 16);
}
__device__ __forceinline__ unsigned short f2bf_exact(float v) {
    return (unsigned short)(__float_as_uint(v) >> 16);
}
__device__ __forceinline__ void gload16(const void* g, void* l) {
    // direct global->LDS DMA, 16B/lane; LDS dest = wave-uniform base + lane*16
    __builtin_amdgcn_global_load_lds(
        (const __attribute__((address_space(1))) unsigned int*)g,
        (__attribute__((address_space(3))) unsigned int*)l, 16, 0, 0);
}

// ---------- prologue kernels ----------
__global__ void init_slots(unsigned* slots) {
    if (threadIdx.x < 2) slots[threadIdx.x] = 0u;
}

__global__ void absmax2_kernel(const float* __restrict__ a, const float* __restrict__ b,
                               int n4, unsigned* __restrict__ slots) {
    const float* p = blockIdx.y ? b : a;
    float m = 0.f;
    const float4* p4 = (const float4*)p;
    for (int i = blockIdx.x * blockDim.x + threadIdx.x; i < n4; i += gridDim.x * blockDim.x) {
        float4 v = p4[i];
        m = fmaxf(m, fmaxf(fmaxf(fabsf(v.x), fabsf(v.y)), fmaxf(fabsf(v.z), fabsf(v.w))));
    }
#pragma unroll
    for (int off = 32; off > 0; off >>= 1)
        m = fmaxf(m, __shfl_xor(m, off, 64));
    if ((threadIdx.x & 63) == 0) atomicMax(slots + blockIdx.y, __float_as_uint(m));
}

__global__ void quant2_kernel(const float* __restrict__ Wa, unsigned short* __restrict__ oa,
                              const float* __restrict__ Wb, unsigned short* __restrict__ ob,
                              int n4, const unsigned* __restrict__ slots) {
    const float* W = blockIdx.y ? Wb : Wa;
    unsigned short* out = blockIdx.y ? ob : oa;
    const float s = __uint_as_float(slots[blockIdx.y]) / 127.0f;
    const float4* W4 = (const float4*)W;
    for (int i = blockIdx.x * blockDim.x + threadIdx.x; i < n4; i += gridDim.x * blockDim.x) {
        float4 v = W4[i];
        u16x4 o;
        o.x = f2bf_exact(fminf(fmaxf(rintf(v.x / s), -127.f), 127.f));
        o.y = f2bf_exact(fminf(fmaxf(rintf(v.y / s), -127.f), 127.f));
        o.z = f2bf_exact(fminf(fmaxf(rintf(v.z / s), -127.f), 127.f));
        o.w = f2bf_exact(fminf(fmaxf(rintf(v.w / s), -127.f), 127.f));
        *(u16x4*)(out + 4 * (size_t)i) = o;
    }
}

// x[M][768] fp32 -> xsplit[M][1536] bf16: hi at col k, lo residual at col 768+k
__global__ void split_x_kernel(const float* __restrict__ x, unsigned short* __restrict__ out,
                               int n4) {
    const float4* x4 = (const float4*)x;
    for (int i = blockIdx.x * blockDim.x + threadIdx.x; i < n4; i += gridDim.x * blockDim.x) {
        int r = i / 192;
        int c = (i - r * 192) * 4;
        float4 v = x4[i];
        u16x4 hi, lo;
        unsigned short h;
        h = f2bf_rne(v.x); hi.x = h; lo.x = f2bf_rne(v.x - bf2f(h));
        h = f2bf_rne(v.y); hi.y = h; lo.y = f2bf_rne(v.y - bf2f(h));
        h = f2bf_rne(v.z); hi.z = h; lo.z = f2bf_rne(v.z - bf2f(h));
        h = f2bf_rne(v.w); hi.w = h; lo.w = f2bf_rne(v.w - bf2f(h));
        size_t base = (size_t)r * 1536 + c;
        *(u16x4*)(out + base) = hi;
        *(u16x4*)(out + base + 768) = lo;
    }
}

// ---------- 256x256 8-phase GEMM (NT): C[m,n] = sum_k A[m,k]*B[n,k mod ldb] ----------
// BK=64, 8 waves (2m x 4n), LDS 128KB dbuf, granule-XOR swizzle (involution, both sides),
// counted vmcnt(8) once per K-tile, setprio around MFMA clusters.
#define MFMA_QUAD(MB, NB)                                                              \
    do {                                                                               \
        _Pragma("unroll") for (int j = 0; j < 4; ++j) {                                \
            _Pragma("unroll") for (int nn = 0; nn < 2; ++nn) {                         \
                acc[(MB) + j][(NB) + nn] =                                             \
                    MFMA_BF16(a[j][0], b[(NB) + nn][0], acc[(MB) + j][(NB) + nn]);     \
                acc[(MB) + j][(NB) + nn] =                                             \
                    MFMA_BF16(a[j][1], b[(NB) + nn][1], acc[(MB) + j][(NB) + nn]);     \
            }                                                                          \
        }                                                                              \
    } while (0)

template <int EPI>
__global__ __launch_bounds__(512, 2) void gemm8p(
    const unsigned short* __restrict__ A, const unsigned short* __restrict__ B,
    const float* __restrict__ bias, const unsigned* __restrict__ wslot,
    const float* __restrict__ sg_ptr, const float* __restrict__ so_ptr,
    unsigned short* __restrict__ out_b, float* __restrict__ out_f,
    int N, int K, int ldb) {
    extern __shared__ char smem[];  // A: [2][256][64] @0 (64KB), B: same @65536

    const int tid = threadIdx.x;
    const int lane = tid & 63;
    const int w = tid >> 6;
    const int wm = (w >> 2) * 128;   // 2x4 wave grid; per-wave C = 128x64
    const int wn = (w & 3) * 64;
    const int lr16 = lane & 15;
    const int lkg = lane >> 4;

    // bijective XCD-aware block swizzle (m204)
    const int gX = gridDim.x;
    const int nwg = gX * gridDim.y;
    const int orig = blockIdx.y * gX + blockIdx.x;
    const int qq = nwg >> 3, rr = nwg & 7;
    const int xcd = orig & 7, idx = orig >> 3;
    const int wg = (xcd < rr ? xcd * (qq + 1) : rr * (qq + 1) + (xcd - rr) * qq) + idx;
    const int m0 = (wg % gX) * 256;
    const int n0 = (wg / gX) * 256;

    const int NT = K >> 6;

    // read-side: row byte base + swizzled granule offsets (granule ^= row&7)
    const int rAb = (wm + lr16) * 128;
    const int rBb = (wn + lr16) * 128;
    const int lxor = lane & 7;               // == row&7 for fragment reads
    const int c0 = (lkg ^ lxor) * 16;        // kk=0 granule
    const int c1 = ((4 + lkg) ^ lxor) * 16;  // kk=1 granule

    // stage-side: lane writes physical granule lane&7 of row ..+(lane>>3);
    // inverse-swizzled global source column granule = (lane&7)^(lane>>3)
    const int rsub = lane >> 3;
    const int csw = ((lane & 7) ^ rsub) * 8;  // bf16-element offset

    const unsigned short* aSrc[2][2];
    const unsigned short* bSrc[2][2];
#pragma unroll
    for (int h = 0; h < 2; ++h)
#pragma unroll
        for (int L = 0; L < 2; ++L) {
            aSrc[h][L] = A + (size_t)(m0 + h * 128 + (w * 2 + L) * 8 + rsub) * K + csw;
            bSrc[h][L] = B + (size_t)(n0 + h * 128 + (w * 2 + L) * 8 + rsub) * ldb + csw;
        }
    const int ldsCh = w * 2048;  // wave's chunk base (2 chunks x 1KB)

#define STAGE_A(P, KC)                                         \
    do {                                                       \
        char* _d = smem + ((P) << 15) + ldsCh;                 \
        gload16(aSrc[0][0] + (KC), _d);                        \
        gload16(aSrc[0][1] + (KC), _d + 1024);                 \
        gload16(aSrc[1][0] + (KC), _d + 16384);                \
        gload16(aSrc[1][1] + (KC), _d + 17408);                \
    } while (0)
#define STAGE_B(P, KC)                                         \
    do {                                                       \
        char* _d = smem + 65536 + ((P) << 15) + ldsCh;         \
        gload16(bSrc[0][0] + (KC), _d);                        \
        gload16(bSrc[0][1] + (KC), _d + 1024);                 \
        gload16(bSrc[1][0] + (KC), _d + 16384);                \
        gload16(bSrc[1][1] + (KC), _d + 17408);                \
    } while (0)

    f32x4 acc[8][4] = {};
    bf16x8 a[4][2], b[4][2];

    // prologue: K-tiles 0 and 1 (16 loads); drain tile 0 (8 oldest), keep tile 1 in flight
    STAGE_A(0, 0);
    STAGE_B(0, 0);
    STAGE_A(1, 64);
    STAGE_B(1, 64);
    asm volatile("s_waitcnt vmcnt(8)" ::: "memory");
    __builtin_amdgcn_s_barrier();

    for (int t = 0; t < NT; ++t) {
        const int p = t & 1;
        const char* Ab = smem + (p << 15);
        const char* Bb = smem + 65536 + (p << 15);
        const bool pre = (t + 2) < NT;
        const int kc = (t + 2) << 6;
        const int bc = (kc >= ldb) ? kc - ldb : kc;  // B wraps (GEMM1: hi|lo share B)

        // ---- phase 0: A m0-3 + B n0-1 reads (12); MFMA quad (0,0) ----
#pragma unroll
        for (int j = 0; j < 4; ++j) {
            a[j][0] = *(const bf16x8*)(Ab + rAb + j * 2048 + c0);
            a[j][1] = *(const bf16x8*)(Ab + rAb + j * 2048 + c1);
        }
#pragma unroll
        for (int n = 0; n < 2; ++n) {
            b[n][0] = *(const bf16x8*)(Bb + rBb + n * 2048 + c0);
            b[n][1] = *(const bf16x8*)(Bb + rBb + n * 2048 + c1);
        }
        __builtin_amdgcn_s_barrier();
        __builtin_amdgcn_s_setprio(1);
        MFMA_QUAD(0, 0);
        __builtin_amdgcn_s_setprio(0);
        __builtin_amdgcn_s_barrier();

        // ---- phase 1: B n2-3 reads (4); MFMA quad (0,2) ----
#pragma unroll
        for (int n = 2; n < 4; ++n) {
            b[n][0] = *(const bf16x8*)(Bb + rBb + n * 2048 + c0);
            b[n][1] = *(const bf16x8*)(Bb + rBb + n * 2048 + c1);
        }
        __builtin_amdgcn_s_barrier();
        __builtin_amdgcn_s_setprio(1);
        MFMA_QUAD(0, 2);
        __builtin_amdgcn_s_setprio(0);
        __builtin_amdgcn_s_barrier();

        // ---- phase 2: A m4-7 reads (8); stage B(t+2) [B reads of this buf done]; quad (4,0) ----
#pragma unroll
        for (int j = 0; j < 4; ++j) {
            a[j][0] = *(const bf16x8*)(Ab + rAb + (4 + j) * 2048 + c0);
            a[j][1] = *(const bf16x8*)(Ab + rAb + (4 + j) * 2048 + c1);
        }
        if (pre) STAGE_B(p, bc);
        __builtin_amdgcn_s_barrier();
        __builtin_amdgcn_s_setprio(1);
        MFMA_QUAD(4, 0);
        __builtin_amdgcn_s_setprio(0);
        __builtin_amdgcn_s_barrier();

        // ---- phase 3: stage A(t+2) [A reads done]; quad (4,2); counted vmcnt ----
        if (pre) STAGE_A(p, kc);
        __builtin_amdgcn_s_barrier();
        __builtin_amdgcn_s_setprio(1);
        MFMA_QUAD(4, 2);
        __builtin_amdgcn_s_setprio(0);
        // drain tile t+1 fully; leave tile t+2's 8 loads in flight
        asm volatile("s_waitcnt vmcnt(8)" ::: "memory");
        __builtin_amdgcn_s_barrier();
    }

    // ---- epilogue ----
    const float ws = __uint_as_float(*wslot) / 127.0f;
    const int mbase = m0 + wm + lkg * 4;
    const int nbase = n0 + wn + lr16;
    if constexpr (EPI == 0) {
        const float sg = *sg_ptr;
#pragma unroll
        for (int mi = 0; mi < 8; ++mi)
#pragma unroll
            for (int ni = 0; ni < 4; ++ni) {
                const int n = nbase + ni * 16;
                const float bn = bias[n];
#pragma unroll
                for (int e = 0; e < 4; ++e) {
                    const int m = mbase + mi * 16 + e;
                    float h = acc[mi][ni][e] * ws + bn;
                    float g = 0.5f * h * (1.0f + erff(h * 0.70710678118654752f));
                    float q = fminf(fmaxf(rintf(g / sg), -128.f), 127.f);
                    out_b[(size_t)m * N + n] = f2bf_exact(q);
                }
            }
    } else {
        const float sg = *sg_ptr;
        const float so = *so_ptr;
        const float sc = sg * ws;
#pragma unroll
        for (int mi = 0; mi < 8; ++mi)
#pragma unroll
            for (int ni = 0; ni < 4; ++ni) {
                const int n = nbase + ni * 16;
                const float bn = bias[n];
#pragma unroll
                for (int e = 0; e < 4; ++e) {
                    const int m = mbase + mi * 16 + e;
                    float y = acc[mi][ni][e] * sc + bn;
                    float q = fminf(fmaxf(rintf(y / so), -128.f), 127.f);
                    out_f[(size_t)m * N + n] = q * so;
                }
            }
    }
#undef STAGE_A
#undef STAGE_B
}

extern "C" void kernel_launch(void* const* d_in, const int* in_sizes, int n_in,
                              void* d_out, int out_size, void* d_ws, size_t ws_size,
                              hipStream_t stream) {
    const float* x  = (const float*)d_in[0];
    const float* W1 = (const float*)d_in[1];
    const float* b1 = (const float*)d_in[2];
    const float* W2 = (const float*)d_in[3];
    const float* b2 = (const float*)d_in[4];
    const float* sg = (const float*)d_in[5];
    const float* so = (const float*)d_in[6];

    const int M = 64 * 196;  // 12544
    const int D = 768;
    const int H = 3072;

    char* ws = (char*)d_ws;
    unsigned* slots = (unsigned*)ws;
    unsigned short* xsplit = (unsigned short*)(ws + 256);   // M x 1536 (hi|lo)
    unsigned short* w1q = xsplit + (size_t)M * 1536;        // H x D
    unsigned short* w2q = w1q + (size_t)H * D;              // D x H
    unsigned short* qact = w2q + (size_t)D * H;             // M x H

    // opt into 128KB dynamic LDS (idempotent, host-side, not a stream op)
    hipFuncSetAttribute(reinterpret_cast<const void*>(gemm8p<0>),
                        hipFuncAttributeMaxDynamicSharedMemorySize, 131072);
    hipFuncSetAttribute(reinterpret_cast<const void*>(gemm8p<1>),
                        hipFuncAttributeMaxDynamicSharedMemorySize, 131072);

    init_slots<<<1, 64, 0, stream>>>(slots);
    const int n4w = (H * D) / 4;
    absmax2_kernel<<<dim3(512, 2), 256, 0, stream>>>(W1, W2, n4w, slots);
    quant2_kernel<<<dim3(1024, 2), 256, 0, stream>>>(W1, w1q, W2, w2q, n4w, slots);
    split_x_kernel<<<2048, 256, 0, stream>>>(x, xsplit, (M * D) / 4);

    dim3 g1(M / 256, H / 256);  // 49 x 12
    gemm8p<0><<<g1, 512, 131072, stream>>>(
        xsplit, w1q, b1, slots + 0, sg, so, qact, nullptr, H, 2 * D, D);

    dim3 g2(M / 256, D / 256);  // 49 x 3
    gemm8p<1><<<g2, 512, 131072, stream>>>(
        qact, w2q, b2, slots + 1, sg, so, nullptr, (float*)d_out, D, H, H);
}

// Round 4
// 344.502 us; speedup vs baseline: 1.0766x; 1.0387x over previous
//
#include <hip/hip_runtime.h>
#include <math.h>

typedef __attribute__((ext_vector_type(8))) short bf16x8;
typedef __attribute__((ext_vector_type(4))) float f32x4;
typedef __attribute__((ext_vector_type(4))) unsigned short u16x4;

#define MFMA_BF16(a, b, c) __builtin_amdgcn_mfma_f32_16x16x32_bf16((a), (b), (c), 0, 0, 0)

// ---------- helpers ----------
__device__ __forceinline__ unsigned short f2bf_rne(float v) {
    unsigned u = __float_as_uint(v);
    unsigned r = u + 0x7FFFu + ((u >> 16) & 1u);
    return (unsigned short)(r >> 16);
}
__device__ __forceinline__ float bf2f(unsigned short b) {
    return __uint_as_float(((unsigned)b) << 16);
}
__device__ __forceinline__ unsigned short f2bf_exact(float v) {
    return (unsigned short)(__float_as_uint(v) >> 16);
}
__device__ __forceinline__ void gload16(const void* g, void* l) {
    __builtin_amdgcn_global_load_lds(
        (const __attribute__((address_space(1))) unsigned int*)g,
        (__attribute__((address_space(3))) unsigned int*)l, 16, 0, 0);
}

// ---------- prologue kernels ----------
__global__ void init_slots(unsigned* slots) {
    if (threadIdx.x < 2) slots[threadIdx.x] = 0u;
}

__global__ void absmax2_kernel(const float* __restrict__ a, const float* __restrict__ b,
                               int n4, unsigned* __restrict__ slots) {
    const float* p = blockIdx.y ? b : a;
    float m = 0.f;
    const float4* p4 = (const float4*)p;
    for (int i = blockIdx.x * blockDim.x + threadIdx.x; i < n4; i += gridDim.x * blockDim.x) {
        float4 v = p4[i];
        m = fmaxf(m, fmaxf(fmaxf(fabsf(v.x), fabsf(v.y)), fmaxf(fabsf(v.z), fabsf(v.w))));
    }
#pragma unroll
    for (int off = 32; off > 0; off >>= 1)
        m = fmaxf(m, __shfl_xor(m, off, 64));
    if ((threadIdx.x & 63) == 0) atomicMax(slots + blockIdx.y, __float_as_uint(m));
}

// blockIdx.y: 0 -> quant W1, 1 -> quant W2, 2 -> split x into bf16 hi|lo
__global__ void prep_kernel(const float* __restrict__ W1, unsigned short* __restrict__ o1,
                            const float* __restrict__ W2, unsigned short* __restrict__ o2,
                            const float* __restrict__ x, unsigned short* __restrict__ xs,
                            int n4w, int n4x, const unsigned* __restrict__ slots) {
    if (blockIdx.y < 2) {
        const float* W = blockIdx.y ? W2 : W1;
        unsigned short* out = blockIdx.y ? o2 : o1;
        const float s = __uint_as_float(slots[blockIdx.y]) / 127.0f;
        const float4* W4 = (const float4*)W;
        for (int i = blockIdx.x * blockDim.x + threadIdx.x; i < n4w; i += gridDim.x * blockDim.x) {
            float4 v = W4[i];
            u16x4 o;
            o.x = f2bf_exact(fminf(fmaxf(rintf(v.x / s), -127.f), 127.f));
            o.y = f2bf_exact(fminf(fmaxf(rintf(v.y / s), -127.f), 127.f));
            o.z = f2bf_exact(fminf(fmaxf(rintf(v.z / s), -127.f), 127.f));
            o.w = f2bf_exact(fminf(fmaxf(rintf(v.w / s), -127.f), 127.f));
            *(u16x4*)(out + 4 * (size_t)i) = o;
        }
    } else {
        const float4* x4 = (const float4*)x;
        for (int i = blockIdx.x * blockDim.x + threadIdx.x; i < n4x; i += gridDim.x * blockDim.x) {
            int r = i / 192;
            int c = (i - r * 192) * 4;
            float4 v = x4[i];
            u16x4 hi, lo;
            unsigned short h;
            h = f2bf_rne(v.x); hi.x = h; lo.x = f2bf_rne(v.x - bf2f(h));
            h = f2bf_rne(v.y); hi.y = h; lo.y = f2bf_rne(v.y - bf2f(h));
            h = f2bf_rne(v.z); hi.z = h; lo.z = f2bf_rne(v.z - bf2f(h));
            h = f2bf_rne(v.w); hi.w = h; lo.w = f2bf_rne(v.w - bf2f(h));
            size_t base = (size_t)r * 1536 + c;
            *(u16x4*)(xs + base) = hi;
            *(u16x4*)(xs + base + 768) = lo;
        }
    }
}

// ---------- 256x256 GEMM (NT): C[m,n] = sum_k A[m,k]*B[n,k mod ldb] ----------
// BK=64, 8 waves (2m x 4n), 128KB LDS dbuf, granule-XOR swizzle both sides,
// 3 barriers/K-tile (lgkm-drain invariant), counted vmcnt(8), setprio on MFMA.
template <int EPI>
__global__ __launch_bounds__(512, 2) void gemm8p(
    const unsigned short* __restrict__ A, const unsigned short* __restrict__ B,
    const float* __restrict__ bias, const unsigned* __restrict__ wslot,
    const float* __restrict__ sg_ptr, const float* __restrict__ so_ptr,
    unsigned short* __restrict__ out_b, float* __restrict__ out_f,
    int N, int K, int ldb) {
    extern __shared__ char smem[];  // A: [2][256][64] @0 (64KB), B: same @65536

    const int tid = threadIdx.x;
    const int lane = tid & 63;
    const int w = tid >> 6;
    const int wm = (w >> 2) * 128;   // 2x4 wave grid; per-wave C = 128x64
    const int wn = (w & 3) * 64;
    const int lr16 = lane & 15;
    const int lkg = lane >> 4;

    // bijective XCD-aware block swizzle (m204)
    const int gX = gridDim.x;
    const int nwg = gX * gridDim.y;
    const int orig = blockIdx.y * gX + blockIdx.x;
    const int qq = nwg >> 3, rr = nwg & 7;
    const int xcd = orig & 7, idx = orig >> 3;
    const int wg = (xcd < rr ? xcd * (qq + 1) : rr * (qq + 1) + (xcd - rr) * qq) + idx;
    const int m0 = (wg % gX) * 256;
    const int n0 = (wg / gX) * 256;

    const int NT = K >> 6;

    // read-side: row byte base + swizzled granule offsets (granule ^= row&7)
    const int rAb = (wm + lr16) * 128;
    const int rBb = (wn + lr16) * 128;
    const int lxor = lane & 7;
    const int c0 = (lkg ^ lxor) * 16;
    const int c1 = ((4 + lkg) ^ lxor) * 16;

    // stage-side: linear LDS dest, inverse-swizzled global source
    const int rsub = lane >> 3;
    const int csw = ((lane & 7) ^ rsub) * 8;

    const unsigned short* aSrc[2][2];
    const unsigned short* bSrc[2][2];
#pragma unroll
    for (int h = 0; h < 2; ++h)
#pragma unroll
        for (int L = 0; L < 2; ++L) {
            aSrc[h][L] = A + (size_t)(m0 + h * 128 + (w * 2 + L) * 8 + rsub) * K + csw;
            bSrc[h][L] = B + (size_t)(n0 + h * 128 + (w * 2 + L) * 8 + rsub) * ldb + csw;
        }
    const int ldsCh = w * 2048;

#define STAGE_A(P, KC)                                         \
    do {                                                       \
        char* _d = smem + ((P) << 15) + ldsCh;                 \
        gload16(aSrc[0][0] + (KC), _d);                        \
        gload16(aSrc[0][1] + (KC), _d + 1024);                 \
        gload16(aSrc[1][0] + (KC), _d + 16384);                \
        gload16(aSrc[1][1] + (KC), _d + 17408);                \
    } while (0)
#define STAGE_B(P, KC)                                         \
    do {                                                       \
        char* _d = smem + 65536 + ((P) << 15) + ldsCh;         \
        gload16(bSrc[0][0] + (KC), _d);                        \
        gload16(bSrc[0][1] + (KC), _d + 1024);                 \
        gload16(bSrc[1][0] + (KC), _d + 16384);                \
        gload16(bSrc[1][1] + (KC), _d + 17408);                \
    } while (0)

    f32x4 acc[8][4] = {};
    bf16x8 a[4][2], b[4][2];

    // prologue: stage K-tiles 0,1; drain tile 0 (leave tile 1's 8 in flight)
    STAGE_A(0, 0);
    STAGE_B(0, 0);
    STAGE_A(1, 64);
    STAGE_B(1, 64);
    asm volatile("s_waitcnt vmcnt(8)" ::: "memory");
    __builtin_amdgcn_s_barrier();

    for (int t = 0; t < NT; ++t) {
        const int p = t & 1;
        const char* Ab = smem + (p << 15);
        const char* Bb = smem + 65536 + (p << 15);
        const bool pre = (t + 2) < NT;
        const int kc = (t + 2) << 6;
        const int bc = (kc >= ldb) ? kc - ldb : kc;

        // ---- Region A: read a0-3 + b0-3; MFMA rows0-3 x all n (32) ----
#pragma unroll
        for (int j = 0; j < 4; ++j) {
            a[j][0] = *(const bf16x8*)(Ab + rAb + j * 2048 + c0);
            a[j][1] = *(const bf16x8*)(Ab + rAb + j * 2048 + c1);
        }
#pragma unroll
        for (int n = 0; n < 4; ++n) {
            b[n][0] = *(const bf16x8*)(Bb + rBb + n * 2048 + c0);
            b[n][1] = *(const bf16x8*)(Bb + rBb + n * 2048 + c1);
        }
        __builtin_amdgcn_s_setprio(1);
#pragma unroll
        for (int kk = 0; kk < 2; ++kk)
#pragma unroll
            for (int j = 0; j < 4; ++j)
#pragma unroll
                for (int n = 0; n < 4; ++n)
                    acc[j][n] = MFMA_BF16(a[j][kk], b[n][kk], acc[j][n]);
        __builtin_amdgcn_s_setprio(0);
        // bar1: every wave's b0-3 reads are data-complete (lgkm before its MFMAs)
        __builtin_amdgcn_s_barrier();
        if (pre) STAGE_B(p, bc);

        // ---- Region B: read a4-7; MFMA rows4-7 x n0-1 (16) ----
#pragma unroll
        for (int j = 0; j < 4; ++j) {
            a[j][0] = *(const bf16x8*)(Ab + rAb + (4 + j) * 2048 + c0);
            a[j][1] = *(const bf16x8*)(Ab + rAb + (4 + j) * 2048 + c1);
        }
        __builtin_amdgcn_s_setprio(1);
#pragma unroll
        for (int kk = 0; kk < 2; ++kk)
#pragma unroll
            for (int j = 0; j < 4; ++j)
#pragma unroll
                for (int n = 0; n < 2; ++n)
                    acc[4 + j][n] = MFMA_BF16(a[j][kk], b[n][kk], acc[4 + j][n]);
        __builtin_amdgcn_s_setprio(0);
        // bar2: every wave's a-reads (rows 0-7) are data-complete
        __builtin_amdgcn_s_barrier();
        if (pre) STAGE_A(p, kc);

        // ---- Region C: MFMA rows4-7 x n2-3 (16) ----
        __builtin_amdgcn_s_setprio(1);
#pragma unroll
        for (int kk = 0; kk < 2; ++kk)
#pragma unroll
            for (int j = 0; j < 4; ++j)
#pragma unroll
                for (int n = 2; n < 4; ++n)
                    acc[4 + j][n] = MFMA_BF16(a[j][kk], b[n][kk], acc[4 + j][n]);
        __builtin_amdgcn_s_setprio(0);
        // drain tile t+1 (8 of t+2 stay in flight); full drain in the tail
        if (pre) {
            asm volatile("s_waitcnt vmcnt(8)" ::: "memory");
        } else {
            asm volatile("s_waitcnt vmcnt(0)" ::: "memory");
        }
        // bar3: all waves' next-tile loads complete before anyone reads them
        __builtin_amdgcn_s_barrier();
    }

    // ---- epilogue ----
    const float ws = __uint_as_float(*wslot) / 127.0f;
    const int mbase = m0 + wm + lkg * 4;
    const int nbase = n0 + wn + lr16;
    if constexpr (EPI == 0) {
        const float sg = *sg_ptr;
#pragma unroll
        for (int mi = 0; mi < 8; ++mi)
#pragma unroll
            for (int ni = 0; ni < 4; ++ni) {
                const int n = nbase + ni * 16;
                const float bn = bias[n];
#pragma unroll
                for (int e = 0; e < 4; ++e) {
                    const int m = mbase + mi * 16 + e;
                    float h = acc[mi][ni][e] * ws + bn;
                    float g = 0.5f * h * (1.0f + erff(h * 0.70710678118654752f));
                    float q = fminf(fmaxf(rintf(g / sg), -128.f), 127.f);
                    out_b[(size_t)m * N + n] = f2bf_exact(q);
                }
            }
    } else {
        const float sg = *sg_ptr;
        const float so = *so_ptr;
        const float sc = sg * ws;
#pragma unroll
        for (int mi = 0; mi < 8; ++mi)
#pragma unroll
            for (int ni = 0; ni < 4; ++ni) {
                const int n = nbase + ni * 16;
                const float bn = bias[n];
#pragma unroll
                for (int e = 0; e < 4; ++e) {
                    const int m = mbase + mi * 16 + e;
                    float y = acc[mi][ni][e] * sc + bn;
                    float q = fminf(fmaxf(rintf(y / so), -128.f), 127.f);
                    out_f[(size_t)m * N + n] = q * so;
                }
            }
    }
#undef STAGE_A
#undef STAGE_B
}

extern "C" void kernel_launch(void* const* d_in, const int* in_sizes, int n_in,
                              void* d_out, int out_size, void* d_ws, size_t ws_size,
                              hipStream_t stream) {
    const float* x  = (const float*)d_in[0];
    const float* W1 = (const float*)d_in[1];
    const float* b1 = (const float*)d_in[2];
    const float* W2 = (const float*)d_in[3];
    const float* b2 = (const float*)d_in[4];
    const float* sg = (const float*)d_in[5];
    const float* so = (const float*)d_in[6];

    const int M = 64 * 196;  // 12544
    const int D = 768;
    const int H = 3072;

    char* ws = (char*)d_ws;
    unsigned* slots = (unsigned*)ws;
    unsigned short* xsplit = (unsigned short*)(ws + 256);   // M x 1536 (hi|lo)
    unsigned short* w1q = xsplit + (size_t)M * 1536;        // H x D
    unsigned short* w2q = w1q + (size_t)H * D;              // D x H
    unsigned short* qact = w2q + (size_t)D * H;             // M x H

    hipFuncSetAttribute(reinterpret_cast<const void*>(gemm8p<0>),
                        hipFuncAttributeMaxDynamicSharedMemorySize, 131072);
    hipFuncSetAttribute(reinterpret_cast<const void*>(gemm8p<1>),
                        hipFuncAttributeMaxDynamicSharedMemorySize, 131072);

    init_slots<<<1, 64, 0, stream>>>(slots);
    const int n4w = (H * D) / 4;
    const int n4x = (M * D) / 4;
    absmax2_kernel<<<dim3(512, 2), 256, 0, stream>>>(W1, W2, n4w, slots);
    prep_kernel<<<dim3(1024, 3), 256, 0, stream>>>(W1, w1q, W2, w2q, x, xsplit,
                                                   n4w, n4x, slots);

    dim3 g1(M / 256, H / 256);  // 49 x 12
    gemm8p<0><<<g1, 512, 131072, stream>>>(
        xsplit, w1q, b1, slots + 0, sg, so, qact, nullptr, H, 2 * D, D);

    dim3 g2(M / 256, D / 256);  // 49 x 3
    gemm8p<1><<<g2, 512, 131072, stream>>>(
        qact, w2q, b2, slots + 1, sg, so, nullptr, (float*)d_out, D, H, H);
}

// Round 5
// 264.478 us; speedup vs baseline: 1.4023x; 1.3026x over previous
//
#include <hip/hip_runtime.h>
#include <math.h>

typedef __attribute__((ext_vector_type(4))) int i32x4;
typedef __attribute__((ext_vector_type(4))) unsigned short u16x4;

#define MFMA_I8(a, b, c) __builtin_amdgcn_mfma_i32_16x16x64_i8((a), (b), (c), 0, 0, 0)

__device__ __forceinline__ void gload16(const void* g, void* l) {
    __builtin_amdgcn_global_load_lds(
        (const __attribute__((address_space(1))) unsigned int*)g,
        (__attribute__((address_space(3))) unsigned int*)l, 16, 0, 0);
}

// ---------- prologue ----------
__global__ void init_slots(unsigned* slots) {
    if (threadIdx.x < 3) slots[threadIdx.x] = 0u;
}

// blockIdx.y: 0 -> W1, 1 -> W2, 2 -> x
__global__ void absmax3_kernel(const float* __restrict__ W1, const float* __restrict__ W2,
                               const float* __restrict__ x, int n4w, int n4x,
                               unsigned* __restrict__ slots) {
    const float* p = (blockIdx.y == 0) ? W1 : (blockIdx.y == 1) ? W2 : x;
    const int n4 = (blockIdx.y == 2) ? n4x : n4w;
    float m = 0.f;
    const float4* p4 = (const float4*)p;
    for (int i = blockIdx.x * blockDim.x + threadIdx.x; i < n4; i += gridDim.x * blockDim.x) {
        float4 v = p4[i];
        m = fmaxf(m, fmaxf(fmaxf(fabsf(v.x), fabsf(v.y)), fmaxf(fabsf(v.z), fabsf(v.w))));
    }
#pragma unroll
    for (int off = 32; off > 0; off >>= 1)
        m = fmaxf(m, __shfl_xor(m, off, 64));
    if ((threadIdx.x & 63) == 0) atomicMax(slots + blockIdx.y, __float_as_uint(m));
}

__device__ __forceinline__ int pack4(float a, float b, float c, float d) {
    return (int)(((unsigned)(unsigned char)(signed char)(int)a) |
                 (((unsigned)(unsigned char)(signed char)(int)b) << 8) |
                 (((unsigned)(unsigned char)(signed char)(int)c) << 16) |
                 (((unsigned)(unsigned char)(signed char)(int)d) << 24));
}

// blockIdx.y: 0 -> quant W1 -> i8, 1 -> quant W2 -> i8, 2 -> split x -> (q1|q2) i8
__global__ void prep_kernel(const float* __restrict__ W1, signed char* __restrict__ o1,
                            const float* __restrict__ W2, signed char* __restrict__ o2,
                            const float* __restrict__ x, signed char* __restrict__ xq,
                            int n4w, int n4x, const unsigned* __restrict__ slots) {
    if (blockIdx.y < 2) {
        const float* W = blockIdx.y ? W2 : W1;
        signed char* out = blockIdx.y ? o2 : o1;
        const float inv_s = 127.0f / __uint_as_float(slots[blockIdx.y]);
        const float4* W4 = (const float4*)W;
        for (int i = blockIdx.x * blockDim.x + threadIdx.x; i < n4w; i += gridDim.x * blockDim.x) {
            float4 v = W4[i];
            float q0 = fminf(fmaxf(rintf(v.x * inv_s), -127.f), 127.f);
            float q1 = fminf(fmaxf(rintf(v.y * inv_s), -127.f), 127.f);
            float q2 = fminf(fmaxf(rintf(v.z * inv_s), -127.f), 127.f);
            float q3 = fminf(fmaxf(rintf(v.w * inv_s), -127.f), 127.f);
            *(int*)(out + 4 * (size_t)i) = pack4(q0, q1, q2, q3);
        }
    } else {
        const float sx = __uint_as_float(slots[2]) / 127.0f;
        const float inv_sx = 1.0f / sx;
        const float r_scale = 255.0f * inv_sx;
        const float4* x4 = (const float4*)x;
        for (int i = blockIdx.x * blockDim.x + threadIdx.x; i < n4x; i += gridDim.x * blockDim.x) {
            int r = i / 192;  // 192 float4 per 768-row
            int c = (i - r * 192) * 4;
            float4 v = x4[i];
            float a0 = rintf(v.x * inv_sx), a1 = rintf(v.y * inv_sx);
            float a2 = rintf(v.z * inv_sx), a3 = rintf(v.w * inv_sx);
            // q1 in [-127,127] by construction (|x| <= 127*sx)
            float b0 = fminf(fmaxf(rintf((v.x - sx * a0) * r_scale), -127.f), 127.f);
            float b1 = fminf(fmaxf(rintf((v.y - sx * a1) * r_scale), -127.f), 127.f);
            float b2 = fminf(fmaxf(rintf((v.z - sx * a2) * r_scale), -127.f), 127.f);
            float b3 = fminf(fmaxf(rintf((v.w - sx * a3) * r_scale), -127.f), 127.f);
            size_t base = (size_t)r * 1536 + c;
            *(int*)(xq + base) = pack4(a0, a1, a2, a3);
            *(int*)(xq + base + 768) = pack4(b0, b1, b2, b3);
        }
    }
}

// ---------- 256x256 i8 GEMM (NT): acc = sum_k A[m,k]*B[n,(k mod bwrap)] ----------
// BK=128 (i8), 8 waves (2m x 4n, 128x64/wave), 128KB LDS dbuf, granule-XOR swizzle,
// 3 barriers/K-tile, counted vmcnt(8), setprio. At t==fold_t: acc *= 255 (dual-i8 fold).
// EPI==0: h=c1*acc+b1[n]; gelu; q=clip(round(g/sg),-128,127) -> i8 out.
// EPI==1: y=c2*acc+b2[n]; out=clip(round(y/so),-128,127)*so -> f32 out.
template <int EPI>
__global__ __launch_bounds__(512, 2) void gemm_i8(
    const signed char* __restrict__ A, const signed char* __restrict__ B,
    const float* __restrict__ bias, const unsigned* __restrict__ slots,
    const float* __restrict__ sg_ptr, const float* __restrict__ so_ptr,
    signed char* __restrict__ out_b, float* __restrict__ out_f,
    int N, int lda, int ldb, int NT, int bwrap, int fold_t) {
    extern __shared__ char smem[];  // A: [2][256][128B] @0 (64KB), B same @65536

    const int tid = threadIdx.x;
    const int lane = tid & 63;
    const int w = tid >> 6;
    const int wm = (w >> 2) * 128;
    const int wn = (w & 3) * 64;
    const int lr16 = lane & 15;
    const int lkg = lane >> 4;

    // bijective XCD-aware swizzle (m204)
    const int gX = gridDim.x;
    const int nwg = gX * gridDim.y;
    const int orig = blockIdx.y * gX + blockIdx.x;
    const int qq = nwg >> 3, rr = nwg & 7;
    const int xcd = orig & 7, idx = orig >> 3;
    const int wg = (xcd < rr ? xcd * (qq + 1) : rr * (qq + 1) + (xcd - rr) * qq) + idx;
    const int m0 = (wg % gX) * 256;
    const int n0 = (wg / gX) * 256;

    // read-side: row base (128B rows) + swizzled granules (granule ^= row&7)
    const int rAb = (wm + lr16) * 128;
    const int rBb = (wn + lr16) * 128;
    const int lxor = lane & 7;
    const int c0 = (lkg ^ lxor) * 16;        // kk=0: k-bytes [lkg*16, +16)
    const int c1 = ((4 + lkg) ^ lxor) * 16;  // kk=1: k-bytes [64+lkg*16, +16)

    // stage-side: linear LDS dest, inverse-swizzled global source granule
    const int rsub = lane >> 3;
    const int csw = ((lane & 7) ^ rsub) * 16;  // byte offset

    const signed char* aSrc[2][2];
    const signed char* bSrc[2][2];
#pragma unroll
    for (int h = 0; h < 2; ++h)
#pragma unroll
        for (int L = 0; L < 2; ++L) {
            aSrc[h][L] = A + (size_t)(m0 + h * 128 + (w * 2 + L) * 8 + rsub) * lda + csw;
            bSrc[h][L] = B + (size_t)(n0 + h * 128 + (w * 2 + L) * 8 + rsub) * ldb + csw;
        }
    const int ldsCh = w * 2048;

#define STAGE_A(P, KC)                                 \
    do {                                               \
        char* _d = smem + ((P) << 15) + ldsCh;         \
        gload16(aSrc[0][0] + (KC), _d);                \
        gload16(aSrc[0][1] + (KC), _d + 1024);         \
        gload16(aSrc[1][0] + (KC), _d + 16384);        \
        gload16(aSrc[1][1] + (KC), _d + 17408);        \
    } while (0)
#define STAGE_B(P, KC)                                 \
    do {                                               \
        char* _d = smem + 65536 + ((P) << 15) + ldsCh; \
        gload16(bSrc[0][0] + (KC), _d);                \
        gload16(bSrc[0][1] + (KC), _d + 1024);         \
        gload16(bSrc[1][0] + (KC), _d + 16384);        \
        gload16(bSrc[1][1] + (KC), _d + 17408);        \
    } while (0)

    i32x4 acc[8][4] = {};
    i32x4 a[4][2], b[4][2];

    // prologue: stage K-tiles 0,1; drain tile 0
    STAGE_A(0, 0);
    STAGE_B(0, 0);
    STAGE_A(1, 128);
    STAGE_B(1, 128);
    asm volatile("s_waitcnt vmcnt(8)" ::: "memory");
    __builtin_amdgcn_s_barrier();

    for (int t = 0; t < NT; ++t) {
        // dual-i8 fold: acc holds part1's exact sum; scale by 255 before part2
        if (t == fold_t) {
#pragma unroll
            for (int mi = 0; mi < 8; ++mi)
#pragma unroll
                for (int ni = 0; ni < 4; ++ni)
                    acc[mi][ni] *= 255;
        }
        const int p = t & 1;
        const char* Ab = smem + (p << 15);
        const char* Bb = smem + 65536 + (p << 15);
        const bool pre = (t + 2) < NT;
        const int kc = (t + 2) << 7;
        const int bc = (kc >= bwrap) ? kc - bwrap : kc;

        // ---- Region A: read a0-3 + b0-3; MFMA rows0-3 x all n (32) ----
#pragma unroll
        for (int j = 0; j < 4; ++j) {
            a[j][0] = *(const i32x4*)(Ab + rAb + j * 2048 + c0);
            a[j][1] = *(const i32x4*)(Ab + rAb + j * 2048 + c1);
        }
#pragma unroll
        for (int n = 0; n < 4; ++n) {
            b[n][0] = *(const i32x4*)(Bb + rBb + n * 2048 + c0);
            b[n][1] = *(const i32x4*)(Bb + rBb + n * 2048 + c1);
        }
        __builtin_amdgcn_s_setprio(1);
#pragma unroll
        for (int kk = 0; kk < 2; ++kk)
#pragma unroll
            for (int j = 0; j < 4; ++j)
#pragma unroll
                for (int n = 0; n < 4; ++n)
                    acc[j][n] = MFMA_I8(a[j][kk], b[n][kk], acc[j][n]);
        __builtin_amdgcn_s_setprio(0);
        __builtin_amdgcn_s_barrier();
        if (pre) STAGE_B(p, bc);

        // ---- Region B: read a4-7; MFMA rows4-7 x n0-1 (16) ----
#pragma unroll
        for (int j = 0; j < 4; ++j) {
            a[j][0] = *(const i32x4*)(Ab + rAb + (4 + j) * 2048 + c0);
            a[j][1] = *(const i32x4*)(Ab + rAb + (4 + j) * 2048 + c1);
        }
        __builtin_amdgcn_s_setprio(1);
#pragma unroll
        for (int kk = 0; kk < 2; ++kk)
#pragma unroll
            for (int j = 0; j < 4; ++j)
#pragma unroll
                for (int n = 0; n < 2; ++n)
                    acc[4 + j][n] = MFMA_I8(a[j][kk], b[n][kk], acc[4 + j][n]);
        __builtin_amdgcn_s_setprio(0);
        __builtin_amdgcn_s_barrier();
        if (pre) STAGE_A(p, kc);

        // ---- Region C: MFMA rows4-7 x n2-3 (16) ----
        __builtin_amdgcn_s_setprio(1);
#pragma unroll
        for (int kk = 0; kk < 2; ++kk)
#pragma unroll
            for (int j = 0; j < 4; ++j)
#pragma unroll
                for (int n = 2; n < 4; ++n)
                    acc[4 + j][n] = MFMA_I8(a[j][kk], b[n][kk], acc[4 + j][n]);
        __builtin_amdgcn_s_setprio(0);
        if (pre) {
            asm volatile("s_waitcnt vmcnt(8)" ::: "memory");
        } else {
            asm volatile("s_waitcnt vmcnt(0)" ::: "memory");
        }
        __builtin_amdgcn_s_barrier();
    }

    // ---- epilogue ----
    const float s1 = __uint_as_float(slots[EPI]) / 127.0f;  // W1 scale (EPI0) / W2 (EPI1)
    const int mbase = m0 + wm + lkg * 4;
    const int nbase = n0 + wn + lr16;
    if constexpr (EPI == 0) {
        const float sx = __uint_as_float(slots[2]) / 127.0f;
        const float c1s = sx * s1 * (1.0f / 255.0f);
        const float inv_sg = 1.0f / *sg_ptr;
#pragma unroll
        for (int mi = 0; mi < 8; ++mi)
#pragma unroll
            for (int ni = 0; ni < 4; ++ni) {
                const int n = nbase + ni * 16;
                const float bn = bias[n];
#pragma unroll
                for (int e = 0; e < 4; ++e) {
                    const int m = mbase + mi * 16 + e;
                    float h = (float)acc[mi][ni][e] * c1s + bn;
                    float g = 0.5f * h * (1.0f + erff(h * 0.70710678118654752f));
                    float q = fminf(fmaxf(rintf(g * inv_sg), -128.f), 127.f);
                    out_b[(size_t)m * N + n] = (signed char)(int)q;
                }
            }
    } else {
        const float sg = *sg_ptr;
        const float so = *so_ptr;
        const float inv_so = 1.0f / so;
        const float c2s = sg * s1;
#pragma unroll
        for (int mi = 0; mi < 8; ++mi)
#pragma unroll
            for (int ni = 0; ni < 4; ++ni) {
                const int n = nbase + ni * 16;
                const float bn = bias[n];
#pragma unroll
                for (int e = 0; e < 4; ++e) {
                    const int m = mbase + mi * 16 + e;
                    float y = (float)acc[mi][ni][e] * c2s + bn;
                    float q = fminf(fmaxf(rintf(y * inv_so), -128.f), 127.f);
                    out_f[(size_t)m * N + n] = q * so;
                }
            }
    }
#undef STAGE_A
#undef STAGE_B
}

extern "C" void kernel_launch(void* const* d_in, const int* in_sizes, int n_in,
                              void* d_out, int out_size, void* d_ws, size_t ws_size,
                              hipStream_t stream) {
    const float* x  = (const float*)d_in[0];
    const float* W1 = (const float*)d_in[1];
    const float* b1 = (const float*)d_in[2];
    const float* W2 = (const float*)d_in[3];
    const float* b2 = (const float*)d_in[4];
    const float* sg = (const float*)d_in[5];
    const float* so = (const float*)d_in[6];

    const int M = 64 * 196;  // 12544
    const int D = 768;
    const int H = 3072;

    char* ws = (char*)d_ws;
    unsigned* slots = (unsigned*)ws;                       // [0]=|W1| [1]=|W2| [2]=|x|
    signed char* xq    = (signed char*)(ws + 256);         // M x 1536 (q1|q2)
    signed char* w1int = xq + (size_t)M * 1536;            // H x D
    signed char* w2int = w1int + (size_t)H * D;            // D x H
    signed char* qact  = w2int + (size_t)D * H;            // M x H

    hipFuncSetAttribute(reinterpret_cast<const void*>(gemm_i8<0>),
                        hipFuncAttributeMaxDynamicSharedMemorySize, 131072);
    hipFuncSetAttribute(reinterpret_cast<const void*>(gemm_i8<1>),
                        hipFuncAttributeMaxDynamicSharedMemorySize, 131072);

    init_slots<<<1, 64, 0, stream>>>(slots);
    const int n4w = (H * D) / 4;
    const int n4x = (M * D) / 4;
    absmax3_kernel<<<dim3(512, 3), 256, 0, stream>>>(W1, W2, x, n4w, n4x, slots);
    prep_kernel<<<dim3(1024, 3), 256, 0, stream>>>(W1, w1int, W2, w2int, x, xq,
                                                   n4w, n4x, slots);

    // GEMM1: A=xq [M][1536] (q1|q2), B=w1int [H][768], NT=12, fold at t=6, B wraps at 768
    dim3 g1(M / 256, H / 256);  // 49 x 12
    gemm_i8<0><<<g1, 512, 131072, stream>>>(
        xq, w1int, b1, slots, sg, so, qact, nullptr, H, 1536, D, 12, D, 6);

    // GEMM2: A=qact [M][3072], B=w2int [D][3072], NT=24, no fold, no wrap
    dim3 g2(M / 256, D / 256);  // 49 x 3
    gemm_i8<1><<<g2, 512, 131072, stream>>>(
        qact, w2int, b2, slots, sg, so, nullptr, (float*)d_out, D, H, H, 24, 1 << 30, -1);
}